// Round 4
// baseline (1253.358 us; speedup 1.0000x reference)
//
#include <hip/hip_runtime.h>
#include <hip/hip_bf16.h>

#define V_PAD  30528
#define S_LEN  512
#define D_DIM  768
#define J_N    12
#define M_ROWS 1024
#define K_MLP  9984
#define N_MLP  9216
#define K_ATT  1536
#define N_ATT  768
#define N_LBL  7

using bf16x8 = __attribute__((ext_vector_type(8))) __bf16;
using f32x4  = __attribute__((ext_vector_type(4))) float;

__device__ __forceinline__ unsigned short f2bf(float f) {
  union { float f; unsigned int u; } c; c.f = f;
  unsigned int u = c.u;
  return (unsigned short)((u + 0x7fffu + ((u >> 16) & 1u)) >> 16); // RNE
}
__device__ __forceinline__ float bf2f(unsigned short h) {
  union { unsigned int u; float f; } c; c.u = (unsigned int)h << 16; return c.f;
}

// counted vmcnt wait (immediate must be a literal in the asm string)
template <int N>
__device__ __forceinline__ void s_waitcnt_vmcnt() {
  static_assert(N >= 0 && N <= 4, "");
  if constexpr (N == 0) asm volatile("s_waitcnt vmcnt(0)" ::: "memory");
  else if constexpr (N == 1) asm volatile("s_waitcnt vmcnt(1)" ::: "memory");
  else if constexpr (N == 2) asm volatile("s_waitcnt vmcnt(2)" ::: "memory");
  else if constexpr (N == 3) asm volatile("s_waitcnt vmcnt(3)" ::: "memory");
  else if constexpr (N == 4) asm volatile("s_waitcnt vmcnt(4)" ::: "memory");
}

// ---- last-occurrence tables (dict semantics) ----
__global__ void build_tables_kernel(const int* __restrict__ ids,
                                    int* __restrict__ last0,
                                    int* __restrict__ last01) {
  int p = blockIdx.x * 256 + threadIdx.x;
  if (p < M_ROWS) {
    int id = ids[p];
    atomicMax(&last01[id], p);
    if (p < S_LEN) atomicMax(&last0[id], p);
  }
}

// ---- seq -> rij[:, 0:768] bf16 ----
__global__ __launch_bounds__(256) void seqrij_kernel(const float* __restrict__ seq,
                                                     unsigned short* __restrict__ rij) {
  int bs = blockIdx.x;
  for (int d = threadIdx.x; d < D_DIM; d += 256)
    rij[(size_t)bs * K_MLP + d] = f2bf(seq[(size_t)bs * D_DIM + d]);
}

// ---- neighbor gather-sum -> rij[:, 768:] bf16 ----
__global__ __launch_bounds__(192)
void gather_kernel(const float* __restrict__ seq, const int* __restrict__ nbr,
                   const int* __restrict__ last0, const int* __restrict__ last01,
                   unsigned short* __restrict__ rij) {
  const int bsj = blockIdx.x;
  const int j  = bsj % J_N;
  const int bs = bsj / J_N;
  const int b  = bs >> 9;
  const int* nb = nbr + (size_t)bsj * 4;
  const int* tab = (b == 0) ? last0 : last01;
  const int s0 = tab[nb[0]], s1 = tab[nb[1]], s2 = tab[nb[2]], s3 = tab[nb[3]];
  const int d4 = threadIdx.x;            // 0..191, covers 768 floats as float4
  float4 a = {0.f, 0.f, 0.f, 0.f};
  if (s0 >= 0) { float4 v = ((const float4*)(seq + (size_t)s0 * D_DIM))[d4]; a.x += v.x; a.y += v.y; a.z += v.z; a.w += v.w; }
  if (s1 >= 0) { float4 v = ((const float4*)(seq + (size_t)s1 * D_DIM))[d4]; a.x += v.x; a.y += v.y; a.z += v.z; a.w += v.w; }
  if (s2 >= 0) { float4 v = ((const float4*)(seq + (size_t)s2 * D_DIM))[d4]; a.x += v.x; a.y += v.y; a.z += v.z; a.w += v.w; }
  if (s3 >= 0) { float4 v = ((const float4*)(seq + (size_t)s3 * D_DIM))[d4]; a.x += v.x; a.y += v.y; a.z += v.z; a.w += v.w; }
  union { unsigned short h[4]; unsigned long long q; } pk;
  pk.h[0] = f2bf(a.x); pk.h[1] = f2bf(a.y); pk.h[2] = f2bf(a.z); pk.h[3] = f2bf(a.w);
  *(unsigned long long*)(rij + (size_t)bs * K_MLP + D_DIM + j * D_DIM + d4 * 4) = pk.q;
}

// ---- NT MFMA GEMM, TMxTN tile, BK=32, fp32 W consumed DIRECTLY.
// A (bf16) staged via global_load_lds (pre-swizzled source, round-1-verified
// conflicts=0). B (fp32) reg-staged with T14 issue-early/write-late split:
//   iter t body: stageA(t+1) glds -> vmcnt(LPSA) [B(t+1) regs ready, FIFO]
//                -> convert+ds_write B(t+1) -> issue B(t+2) reg loads -> MFMA
//   iter top:    vmcnt(NL4) [drains A(t) glds, leaves B(t+1) in flight]
//                -> lgkmcnt(0) -> s_barrier -> sched_barrier(0)
// This fuses the former 552 MB cvt_bf16(W_mlp) pass into the GEMM (W read
// once from HBM as fp32). No split-K: sigmoid gate fused into the epilogue
// (MODE 3), halving C traffic and removing the partial-combine pass.
// MODE 1: tanh(acc+bias) -> outp. MODE 3: sigmoid(acc+bias)*nflat -> outp
// (nflat read back from A's own row, cols D_DIM..D_DIM+N).
template <int MODE, int TM, int TN, bool SWZ>
__global__ __launch_bounds__(256)
void gemm_nt_kernel(const unsigned short* __restrict__ A,
                    const float* __restrict__ Wf,
                    const float* __restrict__ bias,
                    float* __restrict__ outp,
                    int K, int N) {
  constexpr int FM = TM / 32;
  constexpr int FN = TN / 32;
  constexpr int LPSA = TM / 64;      // A global_load_lds per wave per stage
  constexpr int EPT  = TN / 8;       // fp32 elems of B per thread per stage
  constexpr int TPR  = 32 / EPT;     // threads per B row
  constexpr int NL4  = TN / 32;      // float4 loads of B per thread per stage
  constexpr int NCH  = EPT / 8;      // 16B LDS chunks per thread
  __shared__ unsigned short ldsA[2][TM * 32];
  __shared__ unsigned short ldsB[2][TN * 32];
  const int tid  = threadIdx.x;
  const int lane = tid & 63;
  const int w    = tid >> 6;

  int bx = blockIdx.x, by = blockIdx.y;
  if (SWZ) {
    // Group all gridDim.x m-tiles of one n-tile onto ONE XCD, back-to-back:
    // the shared W-panel is fetched from HBM once, then L2-hit.
    // Requires (gridDim.y % 8) == 0.
    const unsigned l   = blockIdx.x + gridDim.x * blockIdx.y;
    const unsigned xcd = l & 7u;
    const unsigned c   = l >> 3;
    const unsigned gpx = gridDim.y >> 3;   // n-groups per XCD
    by = (int)(xcd * gpx + c / gridDim.x);
    bx = (int)(c % gridDim.x);
  }
  const int m0 = bx * TM;
  const int n0 = by * TN;

  f32x4 acc[FM][FN];
#pragma unroll
  for (int i = 0; i < FM; ++i)
#pragma unroll
    for (int j = 0; j < FN; ++j) acc[i][j] = (f32x4){0.f, 0.f, 0.f, 0.f};

  const int lr  = lane >> 2;
  // Bank-conflict swizzle (both-sides, rule 21): LDS slot p of row r holds
  // global 16B chunk p ^ ((r>>1)&3). A: pre-swizzled GLOBAL source column
  // (global_load_lds dest is lane-linear). B: swizzled ds_write slot.
  // Reads use the matching slot. Verified conflicts=0 in rounds 1-2.
  const int lcs = (((lane & 3) ^ ((lane >> 3) & 3)) * 8);   // A staging src col
  const int wm = (w >> 1) * (TM / 2), wn = (w & 1) * (TN / 2);
  const int fr  = lane & 15;
  const int fc  = (((lane >> 4) ^ ((fr >> 1) & 3)) * 8);    // read slot (elems)

  // B reg-staging geometry
  const int br  = tid / TPR;
  const int bc  = (tid % TPR) * EPT;
  const int brs = (br >> 1) & 3;

  auto stageA = [&](int buf, int kk) {
#pragma unroll
    for (int q = 0; q < TM / 64; ++q) {
      const int r = w * (TM / 4) + q * 16;
      const unsigned short* gsrc = A + (size_t)(m0 + r + lr) * K + kk + lcs;
      __builtin_amdgcn_global_load_lds(
          (const __attribute__((address_space(1))) void*)gsrc,
          (__attribute__((address_space(3))) void*)(&ldsA[buf][r * 32]), 16, 0, 0);
    }
  };

  float4 breg[NL4];
  auto loadB = [&](int kk) {
    const float4* g = (const float4*)(Wf + (size_t)(n0 + br) * K + kk + bc);
#pragma unroll
    for (int u = 0; u < NL4; ++u) breg[u] = g[u];
  };
  auto writeB = [&](int buf) {
#pragma unroll
    for (int ch = 0; ch < NCH; ++ch) {
      union { unsigned short h[8]; uint4 q; } pk;
      float4 f0 = breg[2 * ch], f1 = breg[2 * ch + 1];
      pk.h[0] = f2bf(f0.x); pk.h[1] = f2bf(f0.y); pk.h[2] = f2bf(f0.z); pk.h[3] = f2bf(f0.w);
      pk.h[4] = f2bf(f1.x); pk.h[5] = f2bf(f1.y); pk.h[6] = f2bf(f1.z); pk.h[7] = f2bf(f1.w);
      const int slot = ((bc >> 3) + ch) ^ brs;
      *(uint4*)&ldsB[buf][br * 32 + slot * 8] = pk.q;
    }
  };

  auto compute = [&](int buf) {
    bf16x8 aF[FM], bF[FN];
#pragma unroll
    for (int i = 0; i < FM; ++i)
      aF[i] = *(const bf16x8*)&ldsA[buf][(wm + i * 16 + fr) * 32 + fc];
#pragma unroll
    for (int j = 0; j < FN; ++j)
      bF[j] = *(const bf16x8*)&ldsB[buf][(wn + j * 16 + fr) * 32 + fc];
    __builtin_amdgcn_s_setprio(1);
#pragma unroll
    for (int i = 0; i < FM; ++i)
#pragma unroll
      for (int j = 0; j < FN; ++j)
        acc[i][j] = __builtin_amdgcn_mfma_f32_16x16x32_bf16(aF[i], bF[j], acc[i][j], 0, 0, 0);
    __builtin_amdgcn_s_setprio(0);
  };

  const int nt = K >> 5;   // k-iters (BK=32); nt >= 2 for all call sites
  // prologue: B(0) synchronous; A(0) + B(1) in flight
  loadB(0);
  s_waitcnt_vmcnt<0>();
  writeB(0);
  stageA(0, 0);            // LPSA vm ops
  loadB(32);               // NL4 vm ops  -> outstanding: [A(0), B(1)]
  for (int t = 0; t < nt; ++t) {
    const int cur = t & 1;
    // top: drain A(t) glds (leaves B(t+1) reg loads in flight); publish all
    // waves' ds_writes of B(t) and their reads of buf cur^1 via lgkm+barrier.
    if (t + 1 < nt) s_waitcnt_vmcnt<NL4>(); else s_waitcnt_vmcnt<0>();
    asm volatile("s_waitcnt lgkmcnt(0)" ::: "memory");
    __builtin_amdgcn_s_barrier();
    __builtin_amdgcn_sched_barrier(0);   // pin ds_reads behind the rendezvous
    if (t + 1 < nt) {
      stageA(cur ^ 1, (t + 1) * 32);     // outstanding: [B(t+1), A(t+1)]
      s_waitcnt_vmcnt<LPSA>();           // FIFO: drains B(t+1), leaves A(t+1)
      writeB(cur ^ 1);
      if (t + 2 < nt) loadB((t + 2) * 32);  // outstanding: [A(t+1), B(t+2)]
    }
    compute(cur);
  }

  // C/D layout: col = lane&15, row = (lane>>4)*4 + reg  [m89/m91]
#pragma unroll
  for (int i = 0; i < FM; ++i) {
    int gm0 = m0 + wm + i * 16 + (lane >> 4) * 4;
#pragma unroll
    for (int j = 0; j < FN; ++j) {
      int gn = n0 + wn + j * 16 + (lane & 15);
      float bv = bias[gn];
#pragma unroll
      for (int r = 0; r < 4; ++r) {
        size_t idx = (size_t)(gm0 + r) * N + gn;
        float x = acc[i][j][r] + bv;
        if (MODE == 3) {
          float gg = 1.0f / (1.0f + __expf(-x));
          float nv = bf2f(A[(size_t)(gm0 + r) * K + D_DIM + gn]);
          outp[idx] = gg * nv;
        } else {
          outp[idx] = tanhf(x);
        }
      }
    }
  }
}

// ---- attention: c precomputed (gated) -> scores/softmax/mix -> [mix|seq] bf16 ----
__global__ __launch_bounds__(256)
void attn_kernel(const float* __restrict__ seq, const float* __restrict__ c,
                 unsigned short* __restrict__ combined) {
  __shared__ float sc[N_MLP];
  __shared__ float sq[D_DIM];
  __shared__ float ss[J_N];
  const int m = blockIdx.x;
  const int tid = threadIdx.x, lane = tid & 63, w = tid >> 6;
  const float* crow = c + (size_t)m * N_MLP;
  for (int d = tid; d < N_MLP; d += 256) sc[d] = crow[d];
  for (int d = tid; d < D_DIM; d += 256) sq[d] = seq[(size_t)m * D_DIM + d];
  __syncthreads();
#pragma unroll
  for (int jj = 0; jj < 3; ++jj) {
    int j = w * 3 + jj;
    float p = 0.f;
    for (int d = lane; d < D_DIM; d += 64) p += sq[d] * sc[j * D_DIM + d];
#pragma unroll
    for (int off = 32; off > 0; off >>= 1) p += __shfl_down(p, off);
    if (lane == 0) ss[j] = p;
  }
  __syncthreads();
  float mx = ss[0];
#pragma unroll
  for (int j = 1; j < J_N; ++j) mx = fmaxf(mx, ss[j]);
  float aw[J_N]; float sum = 0.f;
#pragma unroll
  for (int j = 0; j < J_N; ++j) { aw[j] = __expf(ss[j] - mx); sum += aw[j]; }
  float inv = 1.f / sum;
  for (int d = tid; d < D_DIM; d += 256) {
    float mix = 0.f;
#pragma unroll
    for (int j = 0; j < J_N; ++j) mix += aw[j] * sc[j * D_DIM + d];
    combined[(size_t)m * K_ATT + d]         = f2bf(mix * inv);
    combined[(size_t)m * K_ATT + D_DIM + d] = f2bf(sq[d]);
  }
}

// ---- classifier (shuffle-reduce) ----
__global__ __launch_bounds__(256)
void cls_kernel(const float* __restrict__ seq, const float* __restrict__ attnout,
                const float* __restrict__ Wc, const float* __restrict__ bc,
                float* __restrict__ out) {
  __shared__ float part[4][N_LBL];
  const int m = blockIdx.x, tid = threadIdx.x, lane = tid & 63, w = tid >> 6;
  float p[N_LBL] = {0.f, 0.f, 0.f, 0.f, 0.f, 0.f, 0.f};
  for (int f = tid; f < K_ATT; f += 256) {
    float v = (f < D_DIM) ? seq[(size_t)m * D_DIM + f]
                          : attnout[(size_t)m * D_DIM + (f - D_DIM)];
#pragma unroll
    for (int l = 0; l < N_LBL; ++l) p[l] += v * Wc[l * K_ATT + f];
  }
#pragma unroll
  for (int l = 0; l < N_LBL; ++l) {
#pragma unroll
    for (int off = 32; off > 0; off >>= 1) p[l] += __shfl_down(p[l], off);
  }
  if (lane == 0) {
#pragma unroll
    for (int l = 0; l < N_LBL; ++l) part[w][l] = p[l];
  }
  __syncthreads();
  if (tid < N_LBL)
    out[(size_t)m * N_LBL + tid] =
        part[0][tid] + part[1][tid] + part[2][tid] + part[3][tid] + bc[tid];
}

extern "C" void kernel_launch(void* const* d_in, const int* in_sizes, int n_in,
                              void* d_out, int out_size, void* d_ws, size_t ws_size,
                              hipStream_t stream) {
  const float* seq   = (const float*)d_in[0];
  const int*   ids   = (const int*)d_in[1];
  const int*   nbr   = (const int*)d_in[2];
  const float* Wmlp  = (const float*)d_in[3];
  const float* bmlp  = (const float*)d_in[4];
  const float* Wattn = (const float*)d_in[5];
  const float* battn = (const float*)d_in[6];
  const float* Wcls  = (const float*)d_in[7];
  const float* bcls  = (const float*)d_in[8];
  float* out = (float*)d_out;
  (void)in_sizes; (void)n_in; (void)out_size; (void)ws_size;

  // Workspace: ~64.5 MB (well under the previously-exercised ~366 MB path)
  char* ws = (char*)d_ws;
  size_t off = 0;
  int* last0  = (int*)(ws + off); off += (size_t)V_PAD * 4;
  int* last01 = (int*)(ws + off); off += (size_t)V_PAD * 4;
  unsigned short* rij = (unsigned short*)(ws + off); off += (size_t)M_ROWS * K_MLP * 2;
  unsigned short* combined = (unsigned short*)(ws + off); off += (size_t)M_ROWS * K_ATT * 2;
  float* attnout = (float*)(ws + off); off += (size_t)M_ROWS * N_ATT * 4;
  float* cgate   = (float*)(ws + off); off += (size_t)M_ROWS * N_MLP * 4;

  hipMemsetAsync(last0, 0xFF, (size_t)2 * V_PAD * 4, stream);
  build_tables_kernel<<<(M_ROWS + 255) / 256, 256, 0, stream>>>(ids, last0, last01);
  seqrij_kernel<<<M_ROWS, 256, 0, stream>>>(seq, rij);
  gather_kernel<<<M_ROWS * J_N, 192, 0, stream>>>(seq, nbr, last0, last01, rij);

  // MLP GEMM: fp32 W direct (no cvt pass), fused sigmoid gate -> cgate.
  // grid (8,72): 576 blocks; SWZ groups 8 m-tiles per n-panel per XCD.
  gemm_nt_kernel<3, 128, 128, true><<<dim3(M_ROWS / 128, N_MLP / 128), 256, 0, stream>>>(
      rij, Wmlp, bmlp, cgate, K_MLP, N_MLP);
  attn_kernel<<<M_ROWS, 256, 0, stream>>>(seq, cgate, combined);
  // attn GEMM: fp32 W direct, tanh epilogue.
  gemm_nt_kernel<1, 64, 64, false><<<dim3(M_ROWS / 64, N_ATT / 64), 256, 0, stream>>>(
      combined, Wattn, battn, attnout, K_ATT, N_ATT);
  cls_kernel<<<M_ROWS, 256, 0, stream>>>(seq, attnout, Wcls, bcls, out);
}

// Round 5
// 1188.760 us; speedup vs baseline: 1.0543x; 1.0543x over previous
//
#include <hip/hip_runtime.h>
#include <hip/hip_bf16.h>

#define V_PAD  30528
#define S_LEN  512
#define D_DIM  768
#define J_N    12
#define M_ROWS 1024
#define K_MLP  9984
#define N_MLP  9216
#define K_ATT  1536
#define N_ATT  768
#define N_LBL  7

using bf16x8 = __attribute__((ext_vector_type(8))) __bf16;
using f32x4  = __attribute__((ext_vector_type(4))) float;

__device__ __forceinline__ unsigned short f2bf(float f) {
  union { float f; unsigned int u; } c; c.f = f;
  unsigned int u = c.u;
  return (unsigned short)((u + 0x7fffu + ((u >> 16) & 1u)) >> 16); // RNE
}
__device__ __forceinline__ float bf2f(unsigned short h) {
  union { unsigned int u; float f; } c; c.u = (unsigned int)h << 16; return c.f;
}

// ---- last-occurrence tables (dict semantics) ----
__global__ void build_tables_kernel(const int* __restrict__ ids,
                                    int* __restrict__ last0,
                                    int* __restrict__ last01) {
  int p = blockIdx.x * 256 + threadIdx.x;
  if (p < M_ROWS) {
    int id = ids[p];
    atomicMax(&last01[id], p);
    if (p < S_LEN) atomicMax(&last0[id], p);
  }
}

// ---- seq -> rij[:, 0:768] bf16 ----
__global__ __launch_bounds__(256) void seqrij_kernel(const float* __restrict__ seq,
                                                     unsigned short* __restrict__ rij) {
  int bs = blockIdx.x;
  for (int d = threadIdx.x; d < D_DIM; d += 256)
    rij[(size_t)bs * K_MLP + d] = f2bf(seq[(size_t)bs * D_DIM + d]);
}

// ---- neighbor gather-sum -> rij[:, 768:] bf16 ----
__global__ __launch_bounds__(192)
void gather_kernel(const float* __restrict__ seq, const int* __restrict__ nbr,
                   const int* __restrict__ last0, const int* __restrict__ last01,
                   unsigned short* __restrict__ rij) {
  const int bsj = blockIdx.x;
  const int j  = bsj % J_N;
  const int bs = bsj / J_N;
  const int b  = bs >> 9;
  const int* nb = nbr + (size_t)bsj * 4;
  const int* tab = (b == 0) ? last0 : last01;
  const int s0 = tab[nb[0]], s1 = tab[nb[1]], s2 = tab[nb[2]], s3 = tab[nb[3]];
  const int d4 = threadIdx.x;            // 0..191, covers 768 floats as float4
  float4 a = {0.f, 0.f, 0.f, 0.f};
  if (s0 >= 0) { float4 v = ((const float4*)(seq + (size_t)s0 * D_DIM))[d4]; a.x += v.x; a.y += v.y; a.z += v.z; a.w += v.w; }
  if (s1 >= 0) { float4 v = ((const float4*)(seq + (size_t)s1 * D_DIM))[d4]; a.x += v.x; a.y += v.y; a.z += v.z; a.w += v.w; }
  if (s2 >= 0) { float4 v = ((const float4*)(seq + (size_t)s2 * D_DIM))[d4]; a.x += v.x; a.y += v.y; a.z += v.z; a.w += v.w; }
  if (s3 >= 0) { float4 v = ((const float4*)(seq + (size_t)s3 * D_DIM))[d4]; a.x += v.x; a.y += v.y; a.z += v.z; a.w += v.w; }
  union { unsigned short h[4]; unsigned long long q; } pk;
  pk.h[0] = f2bf(a.x); pk.h[1] = f2bf(a.y); pk.h[2] = f2bf(a.z); pk.h[3] = f2bf(a.w);
  *(unsigned long long*)(rij + (size_t)bs * K_MLP + D_DIM + j * D_DIM + d4 * 4) = pk.q;
}

// ---- NT MFMA GEMM, TMxTN tile, BK=32, fp32 W consumed DIRECTLY.
// Round-5 structure: EXACT round-1 pipeline (2-buffer LDS, one __syncthreads
// per k-iter, global_load_lds staging — proven 300 µs) with B staged as
// fp32 via global_load_lds (NOT reg-staged — round-4's failure mode) and
// fragment-converted to bf16 in-register with v_cvt_pk_bf16_f32 (T12
// primitive, RNE). Eliminates the 552 MB cvt_bf16(W) pass entirely.
// B bank swizzle for 128B rows (both-sides, rule 21): LDS 16B-slot s of row
// r holds global chunk s ^ (r&7); glds source pre-swizzled per lane; reads
// use matching slot — lane pairs (fr,fr+8) alias 2-way = free [m136].
// A (bf16, 64B rows) keeps the round-1-verified swizzle (conflicts=0).
// MODE 1: tanh(acc+bias) -> outp.
// MODE 3: sigmoid(acc+bias) * nflat -> outp (nflat read from A's own row,
//         cols D_DIM.., bf16) — fuses the gate, removes split-K partials.
template <int MODE, int TM, int TN, bool SWZ>
__global__ __launch_bounds__(256)
void gemm_nt_kernel(const unsigned short* __restrict__ A,
                    const float* __restrict__ Wf,
                    const float* __restrict__ bias,
                    float* __restrict__ outp,
                    int K, int N) {
  constexpr int FM = TM / 32;
  constexpr int FN = TN / 32;
  __shared__ unsigned short ldsA[2][TM * 32];  // bf16, 64B rows
  __shared__ float          ldsB[2][TN * 32];  // fp32, 128B rows
  const int tid  = threadIdx.x;
  const int lane = tid & 63;
  const int w    = tid >> 6;

  int bx = blockIdx.x, by = blockIdx.y;
  if (SWZ) {
    // Group all gridDim.x m-tiles of one n-tile onto ONE XCD, back-to-back:
    // the shared W-panel is fetched from HBM once, then L2-hit.
    // Requires (gridDim.y % 8) == 0.
    const unsigned l   = blockIdx.x + gridDim.x * blockIdx.y;
    const unsigned xcd = l & 7u;
    const unsigned c   = l >> 3;
    const unsigned gpx = gridDim.y >> 3;   // n-groups per XCD
    by = (int)(xcd * gpx + c / gridDim.x);
    bx = (int)(c % gridDim.x);
  }
  const int m0 = bx * TM;
  const int n0 = by * TN;

  f32x4 acc[FM][FN];
#pragma unroll
  for (int i = 0; i < FM; ++i)
#pragma unroll
    for (int j = 0; j < FN; ++j) acc[i][j] = (f32x4){0.f, 0.f, 0.f, 0.f};

  const int lr  = lane >> 2;
  // A swizzle (64B rows): slot p of row r holds chunk p ^ ((r>>1)&3).
  const int lcs = (((lane & 3) ^ ((lane >> 3) & 3)) * 8);   // A staging src col
  // B swizzle (128B rows): slot p of row r holds chunk p ^ (r&7).
  const int bcs = (((lane & 7) ^ ((lane >> 3) & 7)) * 4);   // B staging src col (fp32)
  const int wm = (w >> 1) * (TM / 2), wn = (w & 1) * (TN / 2);
  const int fr  = lane & 15;
  const int fc  = (((lane >> 4) ^ ((fr >> 1) & 3)) * 8);    // A read slot (bf16 elems)
  const int pb0 = (lane >> 4) * 2;                          // B read slot pair base

  auto stage = [&](int buf, int kk) {
#pragma unroll
    for (int q = 0; q < TM / 64; ++q) {   // A tile -> LDS (bf16, 16 rows/instr)
      const int r = w * (TM / 4) + q * 16;
      const unsigned short* gsrc = A + (size_t)(m0 + r + lr) * K + kk + lcs;
      __builtin_amdgcn_global_load_lds(
          (const __attribute__((address_space(1))) void*)gsrc,
          (__attribute__((address_space(3))) void*)(&ldsA[buf][r * 32]), 16, 0, 0);
    }
#pragma unroll
    for (int q = 0; q < TN / 32; ++q) {   // B tile -> LDS (fp32, 8 rows/instr)
      const int r = w * (TN / 4) + q * 8;
      const float* gsrc = Wf + (size_t)(n0 + r + (lane >> 3)) * K + kk + bcs;
      __builtin_amdgcn_global_load_lds(
          (const __attribute__((address_space(1))) void*)gsrc,
          (__attribute__((address_space(3))) void*)(&ldsB[buf][r * 32]), 16, 0, 0);
    }
  };

  auto compute = [&](int buf) {
    bf16x8 aF[FM], bF[FN];
#pragma unroll
    for (int i = 0; i < FM; ++i)
      aF[i] = *(const bf16x8*)&ldsA[buf][(wm + i * 16 + fr) * 32 + fc];
#pragma unroll
    for (int j = 0; j < FN; ++j) {
      const int Rb = wn + j * 16 + fr;
      const float4 b0 = *(const float4*)&ldsB[buf][Rb * 32 + ((pb0 ^ (Rb & 7)) * 4)];
      const float4 b1 = *(const float4*)&ldsB[buf][Rb * 32 + (((pb0 + 1) ^ (Rb & 7)) * 4)];
      union { unsigned int u[4]; bf16x8 v; } cv;
      asm("v_cvt_pk_bf16_f32 %0, %1, %2" : "=v"(cv.u[0]) : "v"(b0.x), "v"(b0.y));
      asm("v_cvt_pk_bf16_f32 %0, %1, %2" : "=v"(cv.u[1]) : "v"(b0.z), "v"(b0.w));
      asm("v_cvt_pk_bf16_f32 %0, %1, %2" : "=v"(cv.u[2]) : "v"(b1.x), "v"(b1.y));
      asm("v_cvt_pk_bf16_f32 %0, %1, %2" : "=v"(cv.u[3]) : "v"(b1.z), "v"(b1.w));
      bF[j] = cv.v;
    }
#pragma unroll
    for (int i = 0; i < FM; ++i)
#pragma unroll
      for (int j = 0; j < FN; ++j)
        acc[i][j] = __builtin_amdgcn_mfma_f32_16x16x32_bf16(aF[i], bF[j], acc[i][j], 0, 0, 0);
  };

  const int nt = K >> 5;   // k-iters (BK=32)
  stage(0, 0);
  for (int t = 0; t < nt; ++t) {
    const int cur = t & 1;
    // __syncthreads drains vmcnt(0)+lgkmcnt(0): buf[cur]'s stage (issued last
    // iter, hidden under last iter's MFMA) is complete, and all waves' reads
    // of buf[cur^1] are done before we overwrite it below.
    __syncthreads();
    if (t + 1 < nt) stage(cur ^ 1, (t + 1) * 32);
    compute(cur);
  }

  // C/D layout: col = lane&15, row = (lane>>4)*4 + reg  [m89/m91]
#pragma unroll
  for (int i = 0; i < FM; ++i) {
    int gm0 = m0 + wm + i * 16 + (lane >> 4) * 4;
#pragma unroll
    for (int j = 0; j < FN; ++j) {
      int gn = n0 + wn + j * 16 + (lane & 15);
      float bv = bias[gn];
#pragma unroll
      for (int r = 0; r < 4; ++r) {
        size_t idx = (size_t)(gm0 + r) * N + gn;
        float x = acc[i][j][r] + bv;
        if (MODE == 3) {
          float gg = 1.0f / (1.0f + __expf(-x));
          float nv = bf2f(A[(size_t)(gm0 + r) * K + D_DIM + gn]);
          outp[idx] = gg * nv;
        } else {
          outp[idx] = tanhf(x);
        }
      }
    }
  }
}

// ---- attention: c precomputed (gated) -> scores/softmax/mix -> [mix|seq] bf16 ----
__global__ __launch_bounds__(256)
void attn_kernel(const float* __restrict__ seq, const float* __restrict__ c,
                 unsigned short* __restrict__ combined) {
  __shared__ float sc[N_MLP];
  __shared__ float sq[D_DIM];
  __shared__ float ss[J_N];
  const int m = blockIdx.x;
  const int tid = threadIdx.x, lane = tid & 63, w = tid >> 6;
  const float* crow = c + (size_t)m * N_MLP;
  for (int d = tid; d < N_MLP; d += 256) sc[d] = crow[d];
  for (int d = tid; d < D_DIM; d += 256) sq[d] = seq[(size_t)m * D_DIM + d];
  __syncthreads();
#pragma unroll
  for (int jj = 0; jj < 3; ++jj) {
    int j = w * 3 + jj;
    float p = 0.f;
    for (int d = lane; d < D_DIM; d += 64) p += sq[d] * sc[j * D_DIM + d];
#pragma unroll
    for (int off = 32; off > 0; off >>= 1) p += __shfl_down(p, off);
    if (lane == 0) ss[j] = p;
  }
  __syncthreads();
  float mx = ss[0];
#pragma unroll
  for (int j = 1; j < J_N; ++j) mx = fmaxf(mx, ss[j]);
  float aw[J_N]; float sum = 0.f;
#pragma unroll
  for (int j = 0; j < J_N; ++j) { aw[j] = __expf(ss[j] - mx); sum += aw[j]; }
  float inv = 1.f / sum;
  for (int d = tid; d < D_DIM; d += 256) {
    float mix = 0.f;
#pragma unroll
    for (int j = 0; j < J_N; ++j) mix += aw[j] * sc[j * D_DIM + d];
    combined[(size_t)m * K_ATT + d]         = f2bf(mix * inv);
    combined[(size_t)m * K_ATT + D_DIM + d] = f2bf(sq[d]);
  }
}

// ---- classifier: Wc staged in LDS (coalesced) + shuffle-reduce ----
__global__ __launch_bounds__(256)
void cls_kernel(const float* __restrict__ seq, const float* __restrict__ attnout,
                const float* __restrict__ Wc, const float* __restrict__ bc,
                float* __restrict__ out) {
  __shared__ float wlds[N_LBL * K_ATT];
  __shared__ float part[4][N_LBL];
  const int m = blockIdx.x, tid = threadIdx.x, lane = tid & 63, w = tid >> 6;
  for (int i = tid; i < N_LBL * K_ATT; i += 256) wlds[i] = Wc[i];
  __syncthreads();
  float p[N_LBL] = {0.f, 0.f, 0.f, 0.f, 0.f, 0.f, 0.f};
  for (int f = tid; f < K_ATT; f += 256) {
    float v = (f < D_DIM) ? seq[(size_t)m * D_DIM + f]
                          : attnout[(size_t)m * D_DIM + (f - D_DIM)];
#pragma unroll
    for (int l = 0; l < N_LBL; ++l) p[l] += v * wlds[l * K_ATT + f];
  }
#pragma unroll
  for (int l = 0; l < N_LBL; ++l) {
#pragma unroll
    for (int off = 32; off > 0; off >>= 1) p[l] += __shfl_down(p[l], off);
  }
  if (lane == 0) {
#pragma unroll
    for (int l = 0; l < N_LBL; ++l) part[w][l] = p[l];
  }
  __syncthreads();
  if (tid < N_LBL)
    out[(size_t)m * N_LBL + tid] =
        part[0][tid] + part[1][tid] + part[2][tid] + part[3][tid] + bc[tid];
}

extern "C" void kernel_launch(void* const* d_in, const int* in_sizes, int n_in,
                              void* d_out, int out_size, void* d_ws, size_t ws_size,
                              hipStream_t stream) {
  const float* seq   = (const float*)d_in[0];
  const int*   ids   = (const int*)d_in[1];
  const int*   nbr   = (const int*)d_in[2];
  const float* Wmlp  = (const float*)d_in[3];
  const float* bmlp  = (const float*)d_in[4];
  const float* Wattn = (const float*)d_in[5];
  const float* battn = (const float*)d_in[6];
  const float* Wcls  = (const float*)d_in[7];
  const float* bcls  = (const float*)d_in[8];
  float* out = (float*)d_out;
  (void)in_sizes; (void)n_in; (void)out_size; (void)ws_size;

  // Workspace: ~65 MB
  char* ws = (char*)d_ws;
  size_t off = 0;
  int* last0  = (int*)(ws + off); off += (size_t)V_PAD * 4;
  int* last01 = (int*)(ws + off); off += (size_t)V_PAD * 4;
  unsigned short* rij = (unsigned short*)(ws + off); off += (size_t)M_ROWS * K_MLP * 2;
  unsigned short* combined = (unsigned short*)(ws + off); off += (size_t)M_ROWS * K_ATT * 2;
  float* attnout = (float*)(ws + off); off += (size_t)M_ROWS * N_ATT * 4;
  float* cgate   = (float*)(ws + off); off += (size_t)M_ROWS * N_MLP * 4;

  hipMemsetAsync(last0, 0xFF, (size_t)2 * V_PAD * 4, stream);
  build_tables_kernel<<<(M_ROWS + 255) / 256, 256, 0, stream>>>(ids, last0, last01);
  seqrij_kernel<<<M_ROWS, 256, 0, stream>>>(seq, rij);
  gather_kernel<<<M_ROWS * J_N, 192, 0, stream>>>(seq, nbr, last0, last01, rij);

  // MLP GEMM: fp32 W direct via glds (no cvt pass), fused sigmoid gate.
  // grid (8,72): SWZ groups the 8 m-tiles of each n-panel onto one XCD.
  gemm_nt_kernel<3, 128, 128, true><<<dim3(M_ROWS / 128, N_MLP / 128), 256, 0, stream>>>(
      rij, Wmlp, bmlp, cgate, K_MLP, N_MLP);
  attn_kernel<<<M_ROWS, 256, 0, stream>>>(seq, cgate, combined);
  // attn GEMM: fp32 W direct, tanh epilogue.
  gemm_nt_kernel<1, 64, 64, false><<<dim3(M_ROWS / 64, N_ATT / 64), 256, 0, stream>>>(
      combined, Wattn, battn, attnout, K_ATT, N_ATT);
  cls_kernel<<<M_ROWS, 256, 0, stream>>>(seq, attnout, Wcls, bcls, out);
}